// Round 1
// 474.929 us; speedup vs baseline: 1.0440x; 1.0440x over previous
//
#include <hip/hip_runtime.h>
#include <hip/hip_bf16.h>
#include <stdint.h>

// SelfAttention: out = softmax((x Wq^T)(x Wk^T)^T / sqrt(D)) (x Wv^T)
// SEQ=8192, D=1024, fp32 in/out. All GEMMs bf16 MFMA.
// R10: port gemm_nt to the 256x256 deep-pipeline structure (T3+T4+T5):
//   - BM=BN=256, BK=64, 512 thr / 8 waves (2x4), per-wave 128x64 (acc[8][4]).
//   - LDS 128 KiB double-buffered; raw s_barrier only (2 per K-tile), never
//     __syncthreads -> no vmcnt(0) drain in the main loop.
//   - counted s_waitcnt vmcnt(8): tile t+2 staged during tile t's phases 3/4,
//     waited at tile t+2's head -> 8 global_load_lds in flight across ~2 full
//     K-tiles of MFMA. vmcnt(0) only on the last tile.
//   - s_setprio(1) around each 16-MFMA cluster.
//   - lgkmcnt(0) + sched_barrier + s_barrier before re-staging a buffer
//     (all waves' ds_reads retired before DMA overwrite).
// Keeps R8/R9: row-rotation LDS swizzle (0 bank conflicts), GROUP_M=8 L2
// grouping, compact q/k/v de-interleave, fused softmax epilogues
// (MODE1 exp2+atomic row sums, MODE2 1/l), split-K=2 PV (grid=256 = 1/CU).
//
// Workspace (~230 MB): x_bf16 16 | Wcat 6 | q 16 | k 16 | v 16 | S 128 | pv 32
//                      | lsum 32KB

#define SEQ 8192
#define DMODEL 1024
#define LOG2E 1.44269504088896340736f
#define GROUP_M 8

typedef __bf16 bf16_t;
typedef __bf16 bf16x8 __attribute__((ext_vector_type(8)));
typedef float f32x4 __attribute__((ext_vector_type(4)));

// ---------------- fp32 -> bf16 convert ----------------
__global__ __launch_bounds__(256)
void convert_f32_bf16(const float* __restrict__ in, bf16_t* __restrict__ out, long n) {
    long i = ((long)blockIdx.x * 256 + threadIdx.x) * 4;
    if (i + 3 < n) {
        const float4 v = *(const float4*)(in + i);
        union { ushort4 u; bf16_t b[4]; } p;
        p.b[0] = (bf16_t)v.x; p.b[1] = (bf16_t)v.y;
        p.b[2] = (bf16_t)v.z; p.b[3] = (bf16_t)v.w;
        *(ushort4*)(out + i) = p.u;
    }
}

// ---------------- fp32 add: out += part ----------------
__global__ __launch_bounds__(256)
void add_f32(float* __restrict__ out, const float* __restrict__ part, long n) {
    long i = ((long)blockIdx.x * 256 + threadIdx.x) * 4;
    if (i + 3 < n) {
        float4 a = *(const float4*)(out + i);
        const float4 b = *(const float4*)(part + i);
        a.x += b.x; a.y += b.y; a.z += b.z; a.w += b.w;
        *(float4*)(out + i) = a;
    }
}

// ---------------- zero fp32 buffer ----------------
__global__ __launch_bounds__(256)
void zero_f32(float* __restrict__ p, int n) {
    int i = blockIdx.x * 256 + threadIdx.x;
    if (i < n) p[i] = 0.0f;
}

// ---------------- NT GEMM: C[M,N] = A[M,K] @ B[N,K]^T ----------------
// 256x256 tile, BK=64, 512 threads (8 waves as 2x4), per-wave 128x64 via
// 8x4 grid of mfma_f32_16x16x32_bf16, two K=32 steps per staged tile.
// Deep pipeline: per K-tile t, 4 phases
//   P1: vmcnt(8) [tile t landed; t+1 may be in flight]; s_barrier;
//       ds_read a0[8],b0[4] (k-step 0); setprio{16 MFMA mi0-3}
//   P2: ds_read a1[8],b1[4] (k-step 1, hidden under MFMAs);
//       setprio{16 MFMA mi4-7}
//   P3: lgkmcnt(0); sched_barrier; s_barrier; stage half of tile t+2 into
//       this buffer; setprio{16 MFMA mi0-3 k1}
//   P4: stage other half; setprio{16 MFMA mi4-7 k1}
// MODE 0: C = alpha*acc. MODE 1: C = exp2(alpha*acc) bf16 + atomic row sums.
// MODE 2: C = acc / lsum[row].
template <typename OutT, int MODE>
__global__ __launch_bounds__(512, 2)
void gemm_nt(const bf16_t* __restrict__ A, const bf16_t* __restrict__ B,
             OutT* __restrict__ C0, OutT* __restrict__ C1,
             float* __restrict__ lsum,
             int M, int N, int Kps, int lda, int ldb, int ldc,
             long plane, int cshift, float alpha)
{
    __shared__ bf16_t As[2][256 * 64];
    __shared__ bf16_t Bs[2][256 * 64];

    const int tid  = threadIdx.x;
    const int wave = tid >> 6;
    const int lane = tid & 63;

    const int nbm = M >> 8, nbn = N >> 8;
    const int tiles = nbm * nbn;
    int bid = blockIdx.x;
    const int sid = bid / tiles;        // split-K id
    bid -= sid * tiles;
    const long kbase = (long)sid * Kps;
    OutT* __restrict__ C = sid ? C1 : C0;

    // grouped swizzle for L2 locality
    const int per_group = GROUP_M * nbn;
    const int gid   = bid / per_group;
    const int rem   = bid - gid * per_group;
    const int first = gid * GROUP_M;
    const int gsz   = min(nbm - first, GROUP_M);
    const int bm    = first + rem % gsz;
    const int bn    = rem / gsz;
    const long row0 = (long)bm * 256;
    const long col0 = (long)bn * 256;

    const int wm = (wave >> 2) * 128;  // wave's 128x64 sub-tile
    const int wn = (wave & 3) * 64;
    const int lr = lane & 15;          // fragment non-K index
    const int lq = lane >> 4;          // quad 0..3 -> k-chunk / row group

    // --- staging addresses: 2048 16B chunks/tile-side, 4 per thread.
    // chunk c = i*512+tid; row r = c>>3 = i*64+rt; phys slot p = tid&7 holds
    // global chunk l = (p+r)&7 (rotation within the 128B row).
    const int rt = tid >> 3;
    const int sl = ((tid & 7) + rt) & 7;
    const bf16_t* pa = A + (row0 + rt) * (long)lda + kbase + sl * 8;
    const bf16_t* pb = B + (col0 + rt) * (long)ldb + kbase + sl * 8;

    // --- LDS read offsets. For row r, wanted chunk g: p = (g - r)&7;
    // r&7 == lr&7 for all mi/ni, so p depends only on (lq,lr,ks).
    const int p0  = (lq - lr) & 7;          // ks=0 chunk = lq
    const int p1  = p0 ^ 4;                 // ks=1 chunk = 4+lq
    const int oA0 = (wm + lr) * 64 + p0 * 8;
    const int oA1 = (wm + lr) * 64 + p1 * 8;
    const int oB0 = (wn + lr) * 64 + p0 * 8;
    const int oB1 = (wn + lr) * 64 + p1 * 8;

    const int nt = Kps >> 6;

    f32x4 acc[8][4] = {};

#define STAGE2(kt, bsel, i0)                                                    \
    {                                                                           \
        _Pragma("unroll")                                                       \
        for (int ii = 0; ii < 2; ++ii) {                                        \
            const int i = (i0) + ii;                                            \
            const bf16_t* ga = pa + (long)(kt) * 64 + (long)i * 64 * lda;       \
            const bf16_t* gb = pb + (long)(kt) * 64 + (long)i * 64 * ldb;       \
            __builtin_amdgcn_global_load_lds(                                   \
                (const __attribute__((address_space(1))) uint32_t*)ga,          \
                (__attribute__((address_space(3))) uint32_t*)(As[bsel] + i * 4096 + tid * 8), \
                16, 0, 0);                                                      \
            __builtin_amdgcn_global_load_lds(                                   \
                (const __attribute__((address_space(1))) uint32_t*)gb,          \
                (__attribute__((address_space(3))) uint32_t*)(Bs[bsel] + i * 4096 + tid * 8), \
                16, 0, 0);                                                      \
        }                                                                       \
    }

    // prologue: stage tiles 0 and 1
    STAGE2(0, 0, 0); STAGE2(0, 0, 2);
    if (nt > 1) { STAGE2(1, 1, 0); STAGE2(1, 1, 2); }

    int cur = 0;
    for (int t = 0; t < nt; ++t) {
        const bf16_t* as = As[cur];
        const bf16_t* bs = Bs[cur];

        // ---- P1: tile t's 8 loads done (tile t+1's 8 may remain in flight)
        if (t + 1 < nt) { asm volatile("s_waitcnt vmcnt(8)" ::: "memory"); }
        else            { asm volatile("s_waitcnt vmcnt(0)" ::: "memory"); }
        __builtin_amdgcn_s_barrier();

        bf16x8 a0[8], b0[4], a1[8], b1[4];
        #pragma unroll
        for (int mi = 0; mi < 8; ++mi)
            a0[mi] = *(const bf16x8*)(as + oA0 + mi * 1024);
        #pragma unroll
        for (int ni = 0; ni < 4; ++ni)
            b0[ni] = *(const bf16x8*)(bs + oB0 + ni * 1024);

        __builtin_amdgcn_s_setprio(1);
        #pragma unroll
        for (int mi = 0; mi < 4; ++mi)
            #pragma unroll
            for (int ni = 0; ni < 4; ++ni)
                acc[mi][ni] = __builtin_amdgcn_mfma_f32_16x16x32_bf16(
                    a0[mi], b0[ni], acc[mi][ni], 0, 0, 0);
        __builtin_amdgcn_s_setprio(0);

        // ---- P2: issue k-step-1 reads under the k0 MFMAs
        #pragma unroll
        for (int mi = 0; mi < 8; ++mi)
            a1[mi] = *(const bf16x8*)(as + oA1 + mi * 1024);
        #pragma unroll
        for (int ni = 0; ni < 4; ++ni)
            b1[ni] = *(const bf16x8*)(bs + oB1 + ni * 1024);

        __builtin_amdgcn_s_setprio(1);
        #pragma unroll
        for (int mi = 4; mi < 8; ++mi)
            #pragma unroll
            for (int ni = 0; ni < 4; ++ni)
                acc[mi][ni] = __builtin_amdgcn_mfma_f32_16x16x32_bf16(
                    a0[mi], b0[ni], acc[mi][ni], 0, 0, 0);
        __builtin_amdgcn_s_setprio(0);

        // ---- P3: all LDS reads of buf cur retired in every wave, then it is
        // safe to DMA tile t+2 over it. Raw barrier: vmcnt NOT drained.
        asm volatile("s_waitcnt lgkmcnt(0)" ::: "memory");
        __builtin_amdgcn_sched_barrier(0);
        __builtin_amdgcn_s_barrier();

        if (t + 2 < nt) STAGE2(t + 2, cur, 0);

        __builtin_amdgcn_s_setprio(1);
        #pragma unroll
        for (int mi = 0; mi < 4; ++mi)
            #pragma unroll
            for (int ni = 0; ni < 4; ++ni)
                acc[mi][ni] = __builtin_amdgcn_mfma_f32_16x16x32_bf16(
                    a1[mi], b1[ni], acc[mi][ni], 0, 0, 0);
        __builtin_amdgcn_s_setprio(0);

        // ---- P4
        if (t + 2 < nt) STAGE2(t + 2, cur, 2);

        __builtin_amdgcn_s_setprio(1);
        #pragma unroll
        for (int mi = 4; mi < 8; ++mi)
            #pragma unroll
            for (int ni = 0; ni < 4; ++ni)
                acc[mi][ni] = __builtin_amdgcn_mfma_f32_16x16x32_bf16(
                    a1[mi], b1[ni], acc[mi][ni], 0, 0, 0);
        __builtin_amdgcn_s_setprio(0);

        cur ^= 1;
    }
#undef STAGE2

    // Epilogue: C/D layout col=lane&15, row=(lane>>4)*4+reg  [m89/m91 verified]
    OutT* __restrict__ Cb = C + (col0 >> cshift) * plane;
    const int ccol0 = (int)(col0 & (((long)1 << cshift) - 1));

    if (MODE == 1) {
        // P' = exp2(alpha*acc); row partial sums -> shfl over lr -> atomicAdd.
        #pragma unroll
        for (int mi = 0; mi < 8; ++mi)
            #pragma unroll
            for (int rg = 0; rg < 4; ++rg) {
                const long r = row0 + wm + mi * 16 + lq * 4 + rg;
                float part = 0.f;
                #pragma unroll
                for (int ni = 0; ni < 4; ++ni) {
                    const int c = ccol0 + wn + ni * 16 + lr;
                    const float e = exp2f(alpha * acc[mi][ni][rg]);
                    part += e;
                    Cb[r * (long)ldc + c] = (OutT)e;
                }
                part += __shfl_xor(part, 1);
                part += __shfl_xor(part, 2);
                part += __shfl_xor(part, 4);
                part += __shfl_xor(part, 8);
                if (lr == 0) atomicAdd(&lsum[r], part);
            }
    } else if (MODE == 2) {
        #pragma unroll
        for (int mi = 0; mi < 8; ++mi)
            #pragma unroll
            for (int rg = 0; rg < 4; ++rg) {
                const long r = row0 + wm + mi * 16 + lq * 4 + rg;
                const float inv = 1.0f / lsum[r];
                #pragma unroll
                for (int ni = 0; ni < 4; ++ni) {
                    const int c = ccol0 + wn + ni * 16 + lr;
                    Cb[r * (long)ldc + c] = (OutT)(acc[mi][ni][rg] * inv);
                }
            }
    } else {
        #pragma unroll
        for (int mi = 0; mi < 8; ++mi)
            #pragma unroll
            for (int ni = 0; ni < 4; ++ni)
                #pragma unroll
                for (int rg = 0; rg < 4; ++rg) {
                    const long r = row0 + wm + mi * 16 + lq * 4 + rg;
                    const int  c = ccol0 + wn + ni * 16 + lr;
                    Cb[r * (long)ldc + c] = (OutT)(alpha * acc[mi][ni][rg]);
                }
    }
}

// ---------------- bf16 transpose (strided in), v -> v^T ----------------
__global__ __launch_bounds__(256)
void transpose_bf16(const bf16_t* __restrict__ in, bf16_t* __restrict__ out,
                    int R, int ldin, int ldout)
{
    __shared__ bf16_t tile[32][33];
    const int tx = threadIdx.x & 31;
    const int ty = threadIdx.x >> 5;   // 0..7
    const int c0 = blockIdx.x * 32;
    const int r0 = blockIdx.y * 32;
    #pragma unroll
    for (int j = 0; j < 32; j += 8)
        tile[ty + j][tx] = in[(long)(r0 + ty + j) * ldin + c0 + tx];
    __syncthreads();
    #pragma unroll
    for (int j = 0; j < 32; j += 8)
        out[(long)(c0 + ty + j) * ldout + r0 + tx] = tile[tx][ty + j];
}

extern "C" void kernel_launch(void* const* d_in, const int* in_sizes, int n_in,
                              void* d_out, int out_size, void* d_ws, size_t ws_size,
                              hipStream_t stream)
{
    const float* x  = (const float*)d_in[0];
    const float* Wq = (const float*)d_in[1];
    const float* Wk = (const float*)d_in[2];
    const float* Wv = (const float*)d_in[3];
    float* out = (float*)d_out;

    char* ws = (char*)d_ws;
    const long XN = (long)SEQ * DMODEL;     // 8,388,608
    const long WN = (long)DMODEL * DMODEL;  // 1,048,576
    const long SN = (long)SEQ * SEQ;        // 67,108,864

    bf16_t* xb   = (bf16_t*)ws;                              // 16MB
    bf16_t* wcat = (bf16_t*)(ws + XN * 2);                   // 6MB [3072,1024]
    bf16_t* qb   = (bf16_t*)(ws + XN * 2 + WN * 6);          // 16MB compact
    bf16_t* kb   = qb + XN;                                  // 16MB compact
    bf16_t* vb   = qb + 2 * XN;                              // 16MB compact
    bf16_t* Sb   = (bf16_t*)(ws + XN * 2 + WN * 6 + XN * 6); // 128MB
    float*  pvp  = (float*)(ws + XN * 2 + WN * 6 + XN * 6 + SN * 2); // 32MB
    float*  lsum = (float*)(ws + XN * 2 + WN * 6 + XN * 6 + SN * 2 + XN * 4); // 32KB
    bf16_t* vtb  = xb;  // v^T overlays x_bf16 (x dead after QKV GEMM)

    const size_t base_need = (size_t)(XN * 2 + WN * 6 + XN * 6 + SN * 2);
    const bool use_split = ws_size >= base_need + XN * 4 + SEQ * 4;
    if (!use_split) lsum = (float*)(ws + base_need);  // reuse pvp slot

    convert_f32_bf16<<<(int)(XN / 4 / 256), 256, 0, stream>>>(x,  xb, XN);
    convert_f32_bf16<<<(int)(WN / 4 / 256), 256, 0, stream>>>(Wq, wcat,          WN);
    convert_f32_bf16<<<(int)(WN / 4 / 256), 256, 0, stream>>>(Wk, wcat + WN,     WN);
    convert_f32_bf16<<<(int)(WN / 4 / 256), 256, 0, stream>>>(Wv, wcat + 2 * WN, WN);
    zero_f32<<<SEQ / 256, 256, 0, stream>>>(lsum, SEQ);

    dim3 blk256(256);
    dim3 blk512(512);
    // qkv = x @ Wcat^T, de-interleaved into compact q|k|v (plane=XN, cshift=10)
    gemm_nt<bf16_t, 0><<<(SEQ / 256) * (3 * DMODEL / 256), blk512, 0, stream>>>(
        xb, wcat, qb, qb, nullptr, SEQ, 3 * DMODEL, DMODEL,
        DMODEL, DMODEL, DMODEL, XN, 10, 1.0f);

    // v^T for the PV GEMM (writes over dead x_bf16)
    transpose_bf16<<<dim3(DMODEL / 32, SEQ / 32), blk256, 0, stream>>>(
        vb, vtb, SEQ, DMODEL, SEQ);

    // P' = exp2((q@k^T) * scale * log2e), bf16; row sums -> lsum (atomic)
    gemm_nt<bf16_t, 1><<<(SEQ / 256) * (SEQ / 256), blk512, 0, stream>>>(
        qb, kb, Sb, Sb, lsum, SEQ, SEQ, DMODEL,
        DMODEL, DMODEL, SEQ, 0, 30, 0.03125f * LOG2E);

    // out = (P' @ v) / l  (PV epilogue applies 1/lsum[row]). Split-K=2 if ws.
    if (use_split) {
        gemm_nt<float, 2><<<2 * (SEQ / 256) * (DMODEL / 256), blk512, 0, stream>>>(
            Sb, vtb, out, pvp, lsum, SEQ, DMODEL, SEQ / 2,
            SEQ, SEQ, DMODEL, 0, 30, 1.0f);
        add_f32<<<(int)(XN / 4 / 256), 256, 0, stream>>>(out, pvp, XN);
    } else {
        gemm_nt<float, 2><<<(SEQ / 256) * (DMODEL / 256), blk512, 0, stream>>>(
            Sb, vtb, out, out, lsum, SEQ, DMODEL, SEQ,
            SEQ, SEQ, DMODEL, 0, 30, 1.0f);
    }
}